// Round 1
// baseline (10884.224 us; speedup 1.0000x reference)
//
#include <hip/hip_runtime.h>

#define BATCH 16
#define Hh 512
#define Ww 512
#define IMG (Hh * Ww)          // 262144 = 2^18
#define TOT (BATCH * IMG)      // 4194304
#define MIN_SIZE 262           // keep strictly greater

// ---------------- vote: m = p1 | (p2 & p3) ----------------
__global__ void vote_kernel(const float* __restrict__ x, unsigned char* __restrict__ m) {
    int g = blockIdx.x * blockDim.x + threadIdx.x;
    if (g >= TOT) return;
    int b   = g >> 18;          // / IMG
    int pix = g & (IMG - 1);
    size_t o = ((size_t)b * 4) * IMG + pix;
    unsigned char p1 = x[o + (size_t)1 * IMG] > 0.5f;
    unsigned char p2 = x[o + (size_t)2 * IMG] > 0.5f;
    unsigned char p3 = x[o + (size_t)3 * IMG] > 0.5f;
    m[g] = (unsigned char)(p1 | (p2 & p3));
}

// ---------------- morphology: 3x3 cross ----------------
// dilate: OR over cross, out-of-bounds = 0
// erode:  AND over cross, out-of-bounds = 1 (cv2 erode default border = foreground)
template <bool ERODE>
__global__ void morph_kernel(const unsigned char* __restrict__ in, unsigned char* __restrict__ out) {
    int g = blockIdx.x * blockDim.x + threadIdx.x;
    if (g >= TOT) return;
    int pix = g & (IMG - 1);
    int y  = pix >> 9;          // / Ww
    int xx = pix & (Ww - 1);
    const unsigned char border = ERODE ? 1 : 0;
    unsigned char c = in[g];
    unsigned char u = (y  > 0     ) ? in[g - Ww] : border;
    unsigned char d = (y  < Hh - 1) ? in[g + Ww] : border;
    unsigned char l = (xx > 0     ) ? in[g - 1 ] : border;
    unsigned char r = (xx < Ww - 1) ? in[g + 1 ] : border;
    out[g] = ERODE ? (unsigned char)(c & u & d & l & r)
                   : (unsigned char)(c | u | d | l | r);
}

// ---------------- union-find CCL ----------------
__device__ __forceinline__ unsigned find_root(unsigned* L, unsigned x) {
    unsigned p = L[x];
    while (p != x) { x = p; p = L[x]; }
    return x;
}

__device__ __forceinline__ void uf_merge(unsigned* L, unsigned a, unsigned b) {
    while (true) {
        a = find_root(L, a);
        b = find_root(L, b);
        if (a == b) return;
        if (a > b) { unsigned t = a; a = b; b = t; }   // a < b
        unsigned old = atomicMin(&L[b], a);
        if (old == b) return;   // attached b -> a
        b = old;                // someone else re-parented b; retry
    }
}

__global__ void init_kernel(const unsigned char* __restrict__ m, unsigned* __restrict__ L) {
    int g = blockIdx.x * blockDim.x + threadIdx.x;
    if (g >= TOT) return;
    L[g] = m[g] ? (unsigned)g : 0xFFFFFFFFu;
}

__global__ void merge_kernel(const unsigned char* __restrict__ m, unsigned* L) {
    int g = blockIdx.x * blockDim.x + threadIdx.x;
    if (g >= TOT) return;
    if (!m[g]) return;
    int pix = g & (IMG - 1);
    int xx = pix & (Ww - 1);
    int y  = pix >> 9;
    if (xx > 0 && m[g - 1 ]) uf_merge(L, (unsigned)g, (unsigned)(g - 1 ));
    if (y  > 0 && m[g - Ww]) uf_merge(L, (unsigned)g, (unsigned)(g - Ww));
}

__global__ void flatten_count_kernel(const unsigned char* __restrict__ m,
                                     unsigned* __restrict__ L,
                                     unsigned* __restrict__ counts) {
    int g = blockIdx.x * blockDim.x + threadIdx.x;
    if (g >= TOT) return;
    if (!m[g]) return;
    unsigned r = find_root(L, (unsigned)g);
    L[g] = r;
    atomicAdd(&counts[r], 1u);
}

__global__ void keep_kernel(const unsigned char* __restrict__ m,
                            const unsigned* __restrict__ L,
                            const unsigned* __restrict__ counts,
                            unsigned char* __restrict__ keep) {
    int g = blockIdx.x * blockDim.x + threadIdx.x;
    if (g >= TOT) return;
    unsigned char k = 0;
    if (m[g]) k = (counts[L[g]] > MIN_SIZE) ? 1 : 0;
    keep[g] = k;
}

__global__ void write_kernel(const unsigned char* __restrict__ keep, float* __restrict__ out) {
    int g = blockIdx.x * blockDim.x + threadIdx.x;
    if (g >= TOT) return;
    out[g] = keep[g] ? 1.0f : 0.0f;
}

extern "C" void kernel_launch(void* const* d_in, const int* in_sizes, int n_in,
                              void* d_out, int out_size, void* d_ws, size_t ws_size,
                              hipStream_t stream) {
    const float* x = (const float*)d_in[0];
    float* out = (float*)d_out;

    // workspace layout: mask0 (4MB u8) | mask1 (4MB u8) | labels (16MB u32)
    unsigned char* mask0 = (unsigned char*)d_ws;
    unsigned char* mask1 = mask0 + TOT;
    unsigned*      L     = (unsigned*)(mask0 + 2 * (size_t)TOT);
    unsigned*      counts = (unsigned*)d_out;   // reused before final write

    const int block = 256;
    const int grid  = (TOT + block - 1) / block;

    // vote -> mask0
    vote_kernel<<<grid, block, 0, stream>>>(x, mask0);
    // close: dilate, erode
    morph_kernel<false><<<grid, block, 0, stream>>>(mask0, mask1);
    morph_kernel<true ><<<grid, block, 0, stream>>>(mask1, mask0);
    // open: erode, dilate
    morph_kernel<true ><<<grid, block, 0, stream>>>(mask0, mask1);
    morph_kernel<false><<<grid, block, 0, stream>>>(mask1, mask0);
    // mask0 = final morphological mask

    // CCL
    init_kernel<<<grid, block, 0, stream>>>(mask0, L);
    merge_kernel<<<grid, block, 0, stream>>>(mask0, L);
    hipMemsetAsync(d_out, 0, (size_t)TOT * sizeof(unsigned), stream);  // counts = 0
    flatten_count_kernel<<<grid, block, 0, stream>>>(mask0, L, counts);

    // size filter -> mask1, then final float write
    keep_kernel<<<grid, block, 0, stream>>>(mask0, L, counts, mask1);
    write_kernel<<<grid, block, 0, stream>>>(mask1, out);
}

// Round 3
// 1317.499 us; speedup vs baseline: 8.2613x; 8.2613x over previous
//
#include <hip/hip_runtime.h>

#define BATCH 16
#define Hh 512
#define Ww 512
#define IMG (Hh * Ww)          // 262144 = 2^18
#define TOT (BATCH * IMG)      // 4194304
#define MIN_SIZE 262           // keep strictly greater

// ---------------- vote: m = p1 | (p2 & p3) ----------------
__global__ void vote_kernel(const float* __restrict__ x, unsigned char* __restrict__ m) {
    int g = blockIdx.x * blockDim.x + threadIdx.x;
    if (g >= TOT) return;
    int b   = g >> 18;          // / IMG
    int pix = g & (IMG - 1);
    size_t o = ((size_t)b * 4) * IMG + pix;
    unsigned char p1 = x[o + (size_t)1 * IMG] > 0.5f;
    unsigned char p2 = x[o + (size_t)2 * IMG] > 0.5f;
    unsigned char p3 = x[o + (size_t)3 * IMG] > 0.5f;
    m[g] = (unsigned char)(p1 | (p2 & p3));
}

// ---------------- morphology: 3x3 cross ----------------
template <bool ERODE>
__global__ void morph_kernel(const unsigned char* __restrict__ in, unsigned char* __restrict__ out) {
    int g = blockIdx.x * blockDim.x + threadIdx.x;
    if (g >= TOT) return;
    int pix = g & (IMG - 1);
    int y  = pix >> 9;          // / Ww
    int xx = pix & (Ww - 1);
    const unsigned char border = ERODE ? 1 : 0;
    unsigned char c = in[g];
    unsigned char u = (y  > 0     ) ? in[g - Ww] : border;
    unsigned char d = (y  < Hh - 1) ? in[g + Ww] : border;
    unsigned char l = (xx > 0     ) ? in[g - 1 ] : border;
    unsigned char r = (xx < Ww - 1) ? in[g + 1 ] : border;
    out[g] = ERODE ? (unsigned char)(c & u & d & l & r)
                   : (unsigned char)(c | u | d | l | r);
}

// ---------------- union-find CCL ----------------
// All concurrent mutation of L is via atomicMin ONLY:
//  - labels monotone decreasing, every written value is a same-set member
//    index that is < the node it's written to -> forest stays acyclic and
//    connectivity is never lost; component root = min pixel index.
__device__ __forceinline__ unsigned find_halve(unsigned* L, unsigned x) {
    while (true) {
        unsigned p = L[x];
        if (p == x) return x;
        unsigned gp = L[p];
        if (gp == p) return p;
        atomicMin(&L[x], gp);   // halving: gp <= p < x, monotone-safe
        x = gp;
    }
}

__device__ __forceinline__ void uf_merge(unsigned* L, unsigned a, unsigned b) {
    while (true) {
        a = find_halve(L, a);
        b = find_halve(L, b);
        if (a == b) return;
        if (a > b) { unsigned t = a; a = b; b = t; }   // a < b
        unsigned old = atomicMin(&L[b], a);
        if (old == b) return;   // attached root b -> a
        b = old;                // b already re-parented; merge a with that set
    }
}

__global__ void init_kernel(const unsigned char* __restrict__ m,
                            unsigned* __restrict__ L,
                            unsigned* __restrict__ counts) {
    int g = blockIdx.x * blockDim.x + threadIdx.x;
    if (g >= TOT) return;
    L[g] = m[g] ? (unsigned)g : 0xFFFFFFFFu;
    counts[g] = 0u;
}

__global__ void merge_kernel(const unsigned char* __restrict__ m, unsigned* L) {
    int g = blockIdx.x * blockDim.x + threadIdx.x;
    if (g >= TOT) return;
    if (!m[g]) return;
    int pix = g & (IMG - 1);
    int xx = pix & (Ww - 1);
    int y  = pix >> 9;
    if (xx > 0 && m[g - 1 ]) uf_merge(L, (unsigned)g, (unsigned)(g - 1 ));
    if (y  > 0 && m[g - Ww]) uf_merge(L, (unsigned)g, (unsigned)(g - Ww));
}

// Post-merge: READ-ONLY root chase (forest is static), write ONLY own slot
// L[g] = root (no other thread writes L[g] -> final labels are exact roots).
// Count via per-block LDS hash: one global atomic per distinct root per block.
#define HASH_SZ 512
__global__ void count_label_kernel(const unsigned char* __restrict__ m,
                                   unsigned* __restrict__ L,
                                   unsigned* __restrict__ counts) {
    __shared__ unsigned keys[HASH_SZ];
    __shared__ unsigned vals[HASH_SZ];
    int tid = threadIdx.x;
    for (int i = tid; i < HASH_SZ; i += blockDim.x) { keys[i] = 0xFFFFFFFFu; vals[i] = 0u; }
    __syncthreads();

    int g = blockIdx.x * blockDim.x + tid;
    if (g < TOT && m[g]) {
        unsigned r = (unsigned)g;
        unsigned p = L[r];
        while (p != r) { r = p; p = L[r]; }   // read-only; concurrent own-slot
                                              // writes only shortcut chains
        L[g] = r;                              // own slot only — race-free
        unsigned h = (r * 2654435761u) & (HASH_SZ - 1);
        while (true) {
            unsigned k = atomicCAS(&keys[h], 0xFFFFFFFFu, r);
            if (k == 0xFFFFFFFFu || k == r) { atomicAdd(&vals[h], 1u); break; }
            h = (h + 1) & (HASH_SZ - 1);
        }
    }
    __syncthreads();
    for (int i = tid; i < HASH_SZ; i += blockDim.x)
        if (keys[i] != 0xFFFFFFFFu) atomicAdd(&counts[keys[i]], vals[i]);
}

__global__ void final_kernel(const unsigned char* __restrict__ m,
                             const unsigned* __restrict__ L,
                             const unsigned* __restrict__ counts,
                             float* __restrict__ out) {
    int g = blockIdx.x * blockDim.x + threadIdx.x;
    if (g >= TOT) return;
    float v = 0.0f;
    if (m[g] && counts[L[g]] > MIN_SIZE) v = 1.0f;
    out[g] = v;
}

extern "C" void kernel_launch(void* const* d_in, const int* in_sizes, int n_in,
                              void* d_out, int out_size, void* d_ws, size_t ws_size,
                              hipStream_t stream) {
    const float* x = (const float*)d_in[0];
    float* out = (float*)d_out;

    // workspace layout: mask0 (4MB u8) | mask1 (4MB u8) | labels (16MB u32)
    unsigned char* mask0 = (unsigned char*)d_ws;
    unsigned char* mask1 = mask0 + TOT;
    unsigned*      L     = (unsigned*)(mask0 + 2 * (size_t)TOT);
    unsigned*      counts = (unsigned*)d_out;   // reused, overwritten by final_kernel

    const int block = 256;
    const int grid  = (TOT + block - 1) / block;

    // vote -> mask0
    vote_kernel<<<grid, block, 0, stream>>>(x, mask0);
    // close: dilate, erode
    morph_kernel<false><<<grid, block, 0, stream>>>(mask0, mask1);
    morph_kernel<true ><<<grid, block, 0, stream>>>(mask1, mask0);
    // open: erode, dilate
    morph_kernel<true ><<<grid, block, 0, stream>>>(mask0, mask1);
    morph_kernel<false><<<grid, block, 0, stream>>>(mask1, mask0);
    // mask0 = final morphological mask

    // CCL
    init_kernel<<<grid, block, 0, stream>>>(mask0, L, counts);
    merge_kernel<<<grid, block, 0, stream>>>(mask0, L);
    count_label_kernel<<<grid, block, 0, stream>>>(mask0, L, counts);
    final_kernel<<<grid, block, 0, stream>>>(mask0, L, counts, out);
}

// Round 4
// 230.765 us; speedup vs baseline: 47.1657x; 5.7093x over previous
//
#include <hip/hip_runtime.h>

#define BATCH 16
#define Hh 512
#define Ww 512
#define IMG (Hh * Ww)          // 262144 = 2^18
#define TOT (BATCH * IMG)      // 4194304
#define MIN_SIZE 262           // keep strictly greater
#define TS 64                  // tile side
#define TPIX (TS * TS)         // 4096 pixels per tile

// ---------------- vote: m = p1 | (p2 & p3), float4-vectorized ----------------
__global__ void vote_kernel(const float4* __restrict__ x, uchar4* __restrict__ m) {
    int q = blockIdx.x * blockDim.x + threadIdx.x;   // quad index
    if (q >= TOT / 4) return;
    int b    = q >> 16;            // / (IMG/4)
    int pix4 = q & 0xFFFF;
    size_t o = (size_t)b * IMG + pix4;               // in float4 units
    float4 a1 = x[o + (size_t)1 * (IMG / 4)];
    float4 a2 = x[o + (size_t)2 * (IMG / 4)];
    float4 a3 = x[o + (size_t)3 * (IMG / 4)];
    uchar4 r;
    r.x = (a1.x > 0.5f) | ((a2.x > 0.5f) & (a3.x > 0.5f));
    r.y = (a1.y > 0.5f) | ((a2.y > 0.5f) & (a3.y > 0.5f));
    r.z = (a1.z > 0.5f) | ((a2.z > 0.5f) & (a3.z > 0.5f));
    r.w = (a1.w > 0.5f) | ((a2.w > 0.5f) & (a3.w > 0.5f));
    m[q] = r;
}

// ---------------- morphology: 3x3 cross ----------------
template <bool ERODE>
__global__ void morph_kernel(const unsigned char* __restrict__ in, unsigned char* __restrict__ out) {
    int g = blockIdx.x * blockDim.x + threadIdx.x;
    if (g >= TOT) return;
    int pix = g & (IMG - 1);
    int y  = pix >> 9;
    int xx = pix & (Ww - 1);
    const unsigned char border = ERODE ? 1 : 0;
    unsigned char c = in[g];
    unsigned char u = (y  > 0     ) ? in[g - Ww] : border;
    unsigned char d = (y  < Hh - 1) ? in[g + Ww] : border;
    unsigned char l = (xx > 0     ) ? in[g - 1 ] : border;
    unsigned char r = (xx < Ww - 1) ? in[g + 1 ] : border;
    out[g] = ERODE ? (unsigned char)(c & u & d & l & r)
                   : (unsigned char)(c | u | d | l | r);
}

// ---------------- union-find primitives (work on any address space) ----------
template <typename P>
__device__ __forceinline__ unsigned uf_find_halve(P L, unsigned x) {
    while (true) {
        unsigned p = L[x];
        if (p == x) return x;
        unsigned gp = L[p];
        if (gp == p) return p;
        atomicMin(&L[x], gp);   // halving: gp <= p < x, monotone-safe
        x = gp;
    }
}

template <typename P>
__device__ __forceinline__ void uf_merge(P L, unsigned a, unsigned b) {
    while (true) {
        a = uf_find_halve(L, a);
        b = uf_find_halve(L, b);
        if (a == b) return;
        if (a > b) { unsigned t = a; a = b; b = t; }   // a < b
        unsigned old = atomicMin(&L[b], a);
        if (old == b) return;   // attached root b -> a
        b = old;                // b already re-parented; retry with that set
    }
}

// ---------------- per-tile CCL entirely in LDS ----------------
// Each block labels one 64x64 tile with LDS union-find, then writes
// L[g] = global index of the pixel's tile-local root (root slot = self-loop).
__global__ __launch_bounds__(256) void tile_ccl_kernel(const unsigned char* __restrict__ m,
                                                       unsigned* __restrict__ L) {
    __shared__ unsigned char msk[TPIX];
    __shared__ unsigned Ll[TPIX];
    int tile = blockIdx.x;            // 16 images * 64 tiles
    int img  = tile >> 6;
    int ty   = (tile >> 3) & 7;
    int tx   = tile & 7;
    unsigned base = (unsigned)img * IMG + (unsigned)ty * TS * Ww + (unsigned)tx * TS;
    int tid = threadIdx.x;

    // load 64x64 mask tile (rows are 64 contiguous, 4-aligned bytes)
    for (int w = tid; w < TPIX / 4; w += 256) {
        int row = w >> 4, c4 = w & 15;
        ((unsigned*)msk)[w] = *(const unsigned*)(m + base + (size_t)row * Ww + c4 * 4);
    }
    __syncthreads();

    for (int i = tid; i < TPIX; i += 256)
        Ll[i] = msk[i] ? (unsigned)i : 0xFFFFFFFFu;
    __syncthreads();

    unsigned* Lp = Ll;
    for (int i = tid; i < TPIX; i += 256) {
        if (!msk[i]) continue;
        int x = i & (TS - 1);
        int y = i >> 6;
        if (x > 0 && msk[i - 1 ]) uf_merge(Lp, (unsigned)i, (unsigned)(i - 1 ));
        if (y > 0 && msk[i - TS]) uf_merge(Lp, (unsigned)i, (unsigned)(i - TS));
    }
    __syncthreads();

    // static forest now: read-only chase, write global label
    for (int i = tid; i < TPIX; i += 256) {
        if (!msk[i]) continue;
        unsigned r = (unsigned)i;
        unsigned p = Ll[r];
        while (p != r) { r = p; p = Ll[r]; }
        unsigned rg = base + (r >> 6) * Ww + (r & (TS - 1));
        L[base + (unsigned)(i >> 6) * Ww + (unsigned)(i & (TS - 1))] = rg;
    }
}

// ---------------- cross-tile boundary merges ----------------
// 14 boundary lines per image (7 vertical x=64k, 7 horizontal y=64k), 512 px each.
__global__ void border_merge_kernel(const unsigned char* __restrict__ m, unsigned* L) {
    int e = blockIdx.x * blockDim.x + threadIdx.x;
    if (e >= BATCH * 14 * 512) return;
    int pos  = e & 511;
    int line = (e >> 9) % 14;
    int img  = e / (14 * 512);
    int x, y, g, n;
    if (line < 7) {            // vertical boundary: merge with left neighbor
        x = (line + 1) * TS; y = pos;
        g = img * IMG + y * Ww + x;
        n = g - 1;
    } else {                   // horizontal boundary: merge with up neighbor
        y = (line - 6) * TS; x = pos;
        g = img * IMG + y * Ww + x;
        n = g - Ww;
    }
    if (m[g] && m[n]) uf_merge(L, (unsigned)g, (unsigned)n);
}

// ---------------- flatten + count via per-block LDS hash ----------------
#define HASH_SZ 512
__global__ void count_label_kernel(const unsigned char* __restrict__ m,
                                   unsigned* __restrict__ L,
                                   unsigned* __restrict__ counts) {
    __shared__ unsigned keys[HASH_SZ];
    __shared__ unsigned vals[HASH_SZ];
    int tid = threadIdx.x;
    for (int i = tid; i < HASH_SZ; i += blockDim.x) { keys[i] = 0xFFFFFFFFu; vals[i] = 0u; }
    __syncthreads();

    int g = blockIdx.x * blockDim.x + tid;
    if (g < TOT && m[g]) {
        unsigned r = (unsigned)g;
        unsigned p = L[r];
        while (p != r) { r = p; p = L[r]; }   // read-only chase (forest static)
        L[g] = r;                              // own slot only — race-free
        unsigned h = (r * 2654435761u) & (HASH_SZ - 1);
        while (true) {
            unsigned k = atomicCAS(&keys[h], 0xFFFFFFFFu, r);
            if (k == 0xFFFFFFFFu || k == r) { atomicAdd(&vals[h], 1u); break; }
            h = (h + 1) & (HASH_SZ - 1);
        }
    }
    __syncthreads();
    for (int i = tid; i < HASH_SZ; i += blockDim.x)
        if (keys[i] != 0xFFFFFFFFu) atomicAdd(&counts[keys[i]], vals[i]);
}

__global__ void final_kernel(const unsigned char* __restrict__ m,
                             const unsigned* __restrict__ L,
                             const unsigned* __restrict__ counts,
                             float* __restrict__ out) {
    int g = blockIdx.x * blockDim.x + threadIdx.x;
    if (g >= TOT) return;
    float v = 0.0f;
    if (m[g] && counts[L[g]] > MIN_SIZE) v = 1.0f;
    out[g] = v;
}

extern "C" void kernel_launch(void* const* d_in, const int* in_sizes, int n_in,
                              void* d_out, int out_size, void* d_ws, size_t ws_size,
                              hipStream_t stream) {
    const float* x = (const float*)d_in[0];
    float* out = (float*)d_out;

    // workspace layout: mask0 (4MB u8) | mask1 (4MB u8) | labels (16MB u32)
    unsigned char* mask0 = (unsigned char*)d_ws;
    unsigned char* mask1 = mask0 + TOT;
    unsigned*      L     = (unsigned*)(mask0 + 2 * (size_t)TOT);
    unsigned*      counts = (unsigned*)d_out;   // reused, overwritten by final_kernel

    const int block = 256;
    const int grid  = (TOT + block - 1) / block;

    // vote -> mask0 (float4 vectorized)
    vote_kernel<<<(TOT / 4 + block - 1) / block, block, 0, stream>>>((const float4*)x, (uchar4*)mask0);
    // close: dilate, erode
    morph_kernel<false><<<grid, block, 0, stream>>>(mask0, mask1);
    morph_kernel<true ><<<grid, block, 0, stream>>>(mask1, mask0);
    // open: erode, dilate
    morph_kernel<true ><<<grid, block, 0, stream>>>(mask0, mask1);
    morph_kernel<false><<<grid, block, 0, stream>>>(mask1, mask0);
    // mask0 = final morphological mask

    // CCL: per-tile LDS union-find, then boundary merges
    tile_ccl_kernel<<<BATCH * 64, 256, 0, stream>>>(mask0, L);
    border_merge_kernel<<<(BATCH * 14 * 512 + block - 1) / block, block, 0, stream>>>(mask0, L);

    hipMemsetAsync(d_out, 0, (size_t)TOT * sizeof(unsigned), stream);  // counts = 0
    count_label_kernel<<<grid, block, 0, stream>>>(mask0, L, counts);
    final_kernel<<<grid, block, 0, stream>>>(mask0, L, counts, out);
}

// Round 5
// 170.786 us; speedup vs baseline: 63.7303x; 1.3512x over previous
//
#include <hip/hip_runtime.h>

typedef unsigned long long u64;
typedef unsigned u32;

#define BATCH 16
#define Hh 512
#define Ww 512
#define IMG (Hh * Ww)          // 262144 = 2^18
#define TOT (BATCH * IMG)      // 4194304
#define WPI (IMG / 64)         // 4096 words per image
#define WROW (Ww / 64)         // 8 words per row
#define MIN_SIZE 262           // keep strictly greater
#define TS 64
#define TPIX (TS * TS)

// ---------------- vote + bitpack: m = p1 | (p2 & p3) ----------------
// wave64 ballot: lane i of each wave holds pixel g0+i -> one u64 word.
__global__ void vote_pack_kernel(const float* __restrict__ x, u64* __restrict__ mp) {
    int g = blockIdx.x * blockDim.x + threadIdx.x;   // exact grid = TOT
    int b = g >> 18, pix = g & (IMG - 1);
    size_t o = ((size_t)b * 4) * IMG + pix;
    bool p1 = x[o + (size_t)IMG]     > 0.5f;
    bool p2 = x[o + 2 * (size_t)IMG] > 0.5f;
    bool p3 = x[o + 3 * (size_t)IMG] > 0.5f;
    u64 bits = __ballot(p1 | (p2 & p3));
    if ((threadIdx.x & 63) == 0) mp[g >> 6] = bits;
}

// ---------------- all 4 morph passes in-LDS, bitwise ----------------
// close(dilate,erode) then open(erode,dilate); 3x3 cross; dilate border=0,
// erode border=1. One block per image, 4096 u64 words in LDS, register-staged
// in-place update (load inputs -> sync -> store results -> sync).
__global__ __launch_bounds__(1024) void morph_all_kernel(const u64* __restrict__ in,
                                                         u64* __restrict__ outp) {
    __shared__ u64 M[WPI];
    int img = blockIdx.x;
    int t = threadIdx.x;
    const u64* gsrc = in + (size_t)img * WPI;
    for (int w = t; w < WPI; w += 1024) M[w] = gsrc[w];
    __syncthreads();

    int w0 = t * 4;                       // each thread owns 4 consecutive words
    #pragma unroll
    for (int pass = 0; pass < 4; ++pass) {
        const bool er = (pass == 1 || pass == 2);
        u64 c[6], up[4], dn[4], res[4];
        #pragma unroll
        for (int k = 0; k < 6; ++k) {
            int w = w0 - 1 + k;
            c[k] = (w >= 0 && w < WPI) ? M[w] : 0;   // only used when in-row
        }
        #pragma unroll
        for (int k = 0; k < 4; ++k) {
            int w = w0 + k;
            up[k] = (w >= WROW)      ? M[w - WROW] : (er ? ~0ULL : 0ULL);
            dn[k] = (w < WPI - WROW) ? M[w + WROW] : (er ? ~0ULL : 0ULL);
        }
        __syncthreads();                  // all reads done
        #pragma unroll
        for (int k = 0; k < 4; ++k) {
            int w = w0 + k, wx = w & 7;
            u64 cc = c[k + 1];
            // bit i <-> pixel x=i: x-1 neighbor = cc<<1 (carry from prev word's bit63)
            u64 lf = (cc << 1) | (wx > 0 ? (c[k] >> 63) : (er ? 1ULL : 0ULL));
            u64 rt = (cc >> 1) | (wx < 7 ? (c[k + 2] << 63) : (er ? (1ULL << 63) : 0ULL));
            res[k] = er ? (cc & lf & rt & up[k] & dn[k])
                        : (cc | lf | rt | up[k] | dn[k]);
        }
        #pragma unroll
        for (int k = 0; k < 4; ++k) M[w0 + k] = res[k];
        __syncthreads();
    }
    u64* gdst = outp + (size_t)img * WPI;
    for (int w = t; w < WPI; w += 1024) gdst[w] = M[w];
}

// ---------------- union-find primitives (LDS or global) ----------------
template <typename P>
__device__ __forceinline__ u32 uf_find_halve(P L, u32 x) {
    while (true) {
        u32 p = L[x];
        if (p == x) return x;
        u32 gp = L[p];
        if (gp == p) return p;
        atomicMin(&L[x], gp);   // halving: gp <= p < x, monotone-safe
        x = gp;
    }
}

template <typename P>
__device__ __forceinline__ void uf_merge(P L, u32 a, u32 b) {
    while (true) {
        a = uf_find_halve(L, a);
        b = uf_find_halve(L, b);
        if (a == b) return;
        if (a > b) { u32 t = a; a = b; b = t; }   // a < b
        u32 old = atomicMin(&L[b], a);
        if (old == b) return;   // attached root b -> a
        b = old;
    }
}

// ---------------- per-tile CCL in LDS (packed mask) + counts zeroing -------
__global__ __launch_bounds__(256) void tile_ccl_kernel(const u64* __restrict__ mp,
                                                       u32* __restrict__ L,
                                                       u32* __restrict__ counts) {
    __shared__ u64 mw[64];        // 64x64 tile = 64 rows x 1 word
    __shared__ u32 Ll[TPIX];
    int tile = blockIdx.x;        // 16 images * 64 tiles
    int img = tile >> 6, ty = (tile >> 3) & 7, tx = tile & 7;
    int tid = threadIdx.x;

    // fold counts=0 init here (1024 blocks x 4096 words covers TOT)
    {
        size_t cbase = (size_t)blockIdx.x * (TOT / 1024);
        for (int i = tid; i < TOT / 1024; i += 256) counts[cbase + i] = 0u;
    }

    for (int r = tid; r < 64; r += 256)
        mw[r] = mp[(size_t)img * WPI + (size_t)(ty * 64 + r) * WROW + tx];
    __syncthreads();

    for (int i = tid; i < TPIX; i += 256)
        Ll[i] = ((mw[i >> 6] >> (i & 63)) & 1) ? (u32)i : 0xFFFFFFFFu;
    __syncthreads();

    u32* Lp = Ll;
    for (int i = tid; i < TPIX; i += 256) {
        if (!((mw[i >> 6] >> (i & 63)) & 1)) continue;
        int xc = i & 63, yr = i >> 6;
        if (xc > 0 && ((mw[yr]     >> (xc - 1)) & 1)) uf_merge(Lp, (u32)i, (u32)(i - 1));
        if (yr > 0 && ((mw[yr - 1] >>  xc     ) & 1)) uf_merge(Lp, (u32)i, (u32)(i - 64));
    }
    __syncthreads();

    u32 base = (u32)img * IMG + (u32)ty * TS * Ww + (u32)tx * TS;
    for (int i = tid; i < TPIX; i += 256) {
        if (!((mw[i >> 6] >> (i & 63)) & 1)) continue;
        u32 r = (u32)i, p = Ll[r];
        while (p != r) { r = p; p = Ll[r]; }     // read-only chase
        L[base + (u32)(i >> 6) * Ww + (u32)(i & 63)] = base + (r >> 6) * Ww + (r & 63);
    }
}

// ---------------- cross-tile boundary merges ----------------
__global__ void border_merge_kernel(const u64* __restrict__ mp, u32* L) {
    int e = blockIdx.x * blockDim.x + threadIdx.x;
    if (e >= BATCH * 14 * 512) return;
    int pos = e & 511, line = (e >> 9) % 14, img = e / (14 * 512);
    int g, n;
    if (line < 7) { int x = (line + 1) * TS, y = pos; g = img * IMG + y * Ww + x; n = g - 1; }
    else          { int y = (line - 6) * TS, x = pos; g = img * IMG + y * Ww + x; n = g - Ww; }
    bool mg = (mp[g >> 6] >> (g & 63)) & 1;
    bool mn = (mp[n >> 6] >> (n & 63)) & 1;
    if (mg && mn) uf_merge(L, (u32)g, (u32)n);
}

// ---------------- flatten + count: wave-aggregated LDS hash ----------------
#define HASH_SZ 512
__global__ __launch_bounds__(256) void count_label_kernel(const u64* __restrict__ mp,
                                                          u32* __restrict__ L,
                                                          u32* __restrict__ counts) {
    __shared__ u32 keys[HASH_SZ];
    __shared__ u32 vals[HASH_SZ];
    int tid = threadIdx.x;
    for (int i = tid; i < HASH_SZ; i += 256) { keys[i] = 0xFFFFFFFFu; vals[i] = 0u; }
    __syncthreads();

    int g = blockIdx.x * 256 + tid;           // exact grid
    bool set = (mp[g >> 6] >> (g & 63)) & 1;
    u32 r = 0xFFFFFFFFu;
    if (set) {
        r = (u32)g;
        u32 p = L[r];
        while (p != r) { r = p; p = L[r]; }   // read-only chase (forest static)
        L[g] = r;                              // own slot only — race-free
    }
    // wave-aggregate: one hash update per distinct root per wave
    bool pending = set;
    while (true) {
        u64 act = __ballot(pending);
        if (!act) break;
        int leader = __ffsll(act) - 1;
        u32 lr = __shfl(r, leader);
        bool mine = pending && (r == lr);
        u64 grp = __ballot(mine);
        if ((tid & 63) == leader) {
            u32 cnt = (u32)__popcll(grp);
            u32 h = (lr * 2654435761u) & (HASH_SZ - 1);
            while (true) {
                u32 k = atomicCAS(&keys[h], 0xFFFFFFFFu, lr);
                if (k == 0xFFFFFFFFu || k == lr) { atomicAdd(&vals[h], cnt); break; }
                h = (h + 1) & (HASH_SZ - 1);
            }
        }
        if (mine) pending = false;
    }
    __syncthreads();
    for (int i = tid; i < HASH_SZ; i += 256)
        if (keys[i] != 0xFFFFFFFFu) atomicAdd(&counts[keys[i]], vals[i]);
}

// ---------------- final: size filter + float write ----------------
// counts aliases out (d_out). Safe: a clobbered counts[r] is either 1.0f
// (bits 1065353216 > 262) or 0.0f (0 <= 262) — exactly r's own keep decision,
// so every reader of counts[r] reaches the same verdict pre- or post-clobber.
__global__ void final_kernel(const u64* __restrict__ mp, const u32* __restrict__ L,
                             const u32* __restrict__ counts, float* __restrict__ out) {
    int g = blockIdx.x * blockDim.x + threadIdx.x;   // exact grid
    bool set = (mp[g >> 6] >> (g & 63)) & 1;
    float v = 0.0f;
    if (set && counts[L[g]] > MIN_SIZE) v = 1.0f;
    out[g] = v;
}

extern "C" void kernel_launch(void* const* d_in, const int* in_sizes, int n_in,
                              void* d_out, int out_size, void* d_ws, size_t ws_size,
                              hipStream_t stream) {
    const float* x = (const float*)d_in[0];
    float* out = (float*)d_out;

    // ws layout: maskP0 (512KB) | maskP1 (512KB) | L (16MB)
    u64* mp0 = (u64*)d_ws;
    u64* mp1 = mp0 + TOT / 64;
    u32* L   = (u32*)(mp1 + TOT / 64);
    u32* counts = (u32*)d_out;     // aliases out — see final_kernel comment

    const int block = 256;

    vote_pack_kernel<<<TOT / block, block, 0, stream>>>(x, mp0);
    morph_all_kernel<<<BATCH, 1024, 0, stream>>>(mp0, mp1);           // mp1 = final mask
    tile_ccl_kernel<<<BATCH * 64, block, 0, stream>>>(mp1, L, counts); // + counts=0
    border_merge_kernel<<<(BATCH * 14 * 512 + block - 1) / block, block, 0, stream>>>(mp1, L);
    count_label_kernel<<<TOT / block, block, 0, stream>>>(mp1, L, counts);
    final_kernel<<<TOT / block, block, 0, stream>>>(mp1, L, counts, out);
}

// Round 6
// 141.455 us; speedup vs baseline: 76.9447x; 1.2073x over previous
//
#include <hip/hip_runtime.h>

typedef unsigned long long u64;
typedef unsigned u32;

#define BATCH 16
#define Hh 512
#define Ww 512
#define IMG (Hh * Ww)          // 262144 = 2^18
#define TOT (BATCH * IMG)      // 4194304
#define WPI (IMG / 64)         // 4096 words per image
#define WROW (Ww / 64)         // 8 words per row
#define MIN_SIZE 262           // keep strictly greater
#define TS 64
#define TPIX (TS * TS)

#define BAND 64
#define HALO 4
#define BROWS (BAND + 2 * HALO)     // 72
#define BWORDS (BROWS * WROW)       // 576

// run start within a 64-bit row word: nearest zero at-or-below bit s, +1.
// (bit s must be set in `bits`.)
__device__ __forceinline__ int runstart(u64 bits, int s) {
    u64 ms = (s >= 63) ? ~0ULL : ((1ULL << (s + 1)) - 1);
    u64 nz = ~bits & ms;
    return nz ? (64 - __clzll(nz)) : 0;
}

// one morph step for word w (band-local), row rr (image coords)
__device__ __forceinline__ u64 morph_word(const u64* M, int w, int rr, bool er) {
    const u64 B = er ? ~0ULL : 0ULL;
    int wx = w & 7;
    u64 cc = M[w];
    u64 lf = (cc << 1) | (wx > 0 ? (M[w - 1] >> 63) : (er ? 1ULL : 0ULL));
    u64 rt = (cc >> 1) | (wx < 7 ? (M[w + 1] << 63) : (er ? (1ULL << 63) : 0ULL));
    u64 up = (rr == 0)      ? B : (w >= WROW          ? M[w - WROW] : B);
    u64 dn = (rr == Hh - 1) ? B : (w < BWORDS - WROW  ? M[w + WROW] : B);
    return er ? (cc & lf & rt & up & dn) : (cc | lf | rt | up | dn);
}

// ---------------- fused vote + 4 morph passes, banded ----------------
// 8 bands/image x 16 images = 128 blocks, 512 threads. Band = 64 owned rows
// + 4 halo rows each side. Vote computed during load via wave64 ballot.
__global__ __launch_bounds__(512) void vote_morph_kernel(const float* __restrict__ x,
                                                         u64* __restrict__ mp) {
    __shared__ u64 M[BWORDS];
    int band = blockIdx.x;
    int img  = band >> 3;
    int r0   = (band & 7) * BAND;
    int t    = threadIdx.x;
    int lane = t & 63;
    int wv   = t >> 6;                    // 8 waves

    const float* xb = x + (size_t)img * 4 * IMG;
    for (int w = wv; w < BWORDS; w += 8) {          // word-col = wv (uniform)
        int rr = r0 - HALO + (w >> 3);
        u64 bits = 0;
        if (rr >= 0 && rr < Hh) {                   // wave-uniform branch
            size_t p = (size_t)rr * Ww + (size_t)(w & 7) * 64 + lane;
            bool p1 = xb[p + (size_t)IMG]     > 0.5f;
            bool p2 = xb[p + 2 * (size_t)IMG] > 0.5f;
            bool p3 = xb[p + 3 * (size_t)IMG] > 0.5f;
            bits = __ballot(p1 | (p2 & p3));
        }
        if (lane == 0) M[w] = bits;
    }
    __syncthreads();

    int w1 = t;                    // < 576 always (512 threads)
    int w2 = t + 512;              // threads 0..63 own a 2nd word
    bool has2 = (w2 < BWORDS);
    int rr1 = r0 - HALO + (w1 >> 3);
    int rr2 = r0 - HALO + (w2 >> 3);
    #pragma unroll
    for (int pass = 0; pass < 4; ++pass) {
        const bool er = (pass == 1 || pass == 2);   // close: D,E  open: E,D
        u64 res1 = morph_word(M, w1, rr1, er);
        u64 res2 = has2 ? morph_word(M, w2, rr2, er) : 0;
        __syncthreads();
        M[w1] = res1;
        if (has2) M[w2] = res2;
        __syncthreads();
    }

    u64* dst = mp + (size_t)img * WPI + (size_t)r0 * WROW;
    dst[t] = M[t + HALO * WROW];   // 512 owned words, 1/thread
}

// ---------------- union-find primitives (LDS or global) ----------------
template <typename P>
__device__ __forceinline__ u32 uf_find_halve(P L, u32 x) {
    while (true) {
        u32 p = L[x];
        if (p == x) return x;
        u32 gp = L[p];
        if (gp == p) return p;
        atomicMin(&L[x], gp);   // halving: gp <= p < x, monotone-safe
        x = gp;
    }
}

template <typename P>
__device__ __forceinline__ void uf_merge(P L, u32 a, u32 b) {
    while (true) {
        a = uf_find_halve(L, a);
        b = uf_find_halve(L, b);
        if (a == b) return;
        if (a > b) { u32 t = a; a = b; b = t; }   // a < b
        u32 old = atomicMin(&L[b], a);
        if (old == b) return;   // attached root b -> a
        b = old;
    }
}

// ---------------- per-tile run-based CCL in LDS ----------------
// Nodes = run starts within each 64-px row word. Row-pair links = maximal
// segments of (rowA & rowB): one union per segment.
__global__ __launch_bounds__(256) void tile_ccl_kernel(const u64* __restrict__ mp,
                                                       u32* __restrict__ L,
                                                       u32* __restrict__ counts) {
    __shared__ u64 mw[64];
    __shared__ u32 Ll[TPIX];
    int tile = blockIdx.x;        // 16 images * 64 tiles
    int img = tile >> 6, ty = (tile >> 3) & 7, tx = tile & 7;
    int tid = threadIdx.x;

    // fold counts=0 (1024 blocks x 4 KiB of u32 = 16 MiB), vectorized
    {
        uint4* c4 = (uint4*)counts + (size_t)blockIdx.x * 1024;
        for (int i = tid; i < 1024; i += 256) c4[i] = make_uint4(0u, 0u, 0u, 0u);
    }

    if (tid < 64)
        mw[tid] = mp[(size_t)img * WPI + (size_t)(ty * 64 + tid) * WROW + tx];
    __syncthreads();

    for (int i = tid; i < TPIX; i += 256) Ll[i] = (u32)i;
    __syncthreads();

    // merge adjacent-row runs: thread r handles row pair (r-1, r)
    if (tid >= 1 && tid < 64) {
        int r = tid;
        u64 a = mw[r - 1], b = mw[r];
        u64 ov = a & b;
        u64 seg = ov & ~(ov << 1);              // segment starts
        while (seg) {
            int s = __ffsll(seg) - 1; seg &= seg - 1;
            u32 na = (u32)((r - 1) * 64 + runstart(a, s));
            u32 nb = (u32)(r * 64 + runstart(b, s));
            uf_merge(Ll, na, nb);
        }
    }
    __syncthreads();

    // flatten run-start nodes (own-slot writes; concurrent reads benign)
    if (tid < 64) {
        int r = tid;
        u64 st = mw[r] & ~(mw[r] << 1);         // run starts in this row
        while (st) {
            int s = __ffsll(st) - 1; st &= st - 1;
            u32 n = (u32)(r * 64 + s);
            u32 rt = n, p = Ll[rt];
            while (p != rt) { rt = p; p = Ll[rt]; }
            Ll[n] = rt;
        }
    }
    __syncthreads();

    // per-pixel global label = root of its run-start node
    u32 base = (u32)img * IMG + (u32)ty * TS * Ww + (u32)tx * TS;
    for (int i = tid; i < TPIX; i += 256) {
        int r = i >> 6, xbit = i & 63;
        u64 bits = mw[r];
        if (!((bits >> xbit) & 1)) continue;
        u32 rt = Ll[r * 64 + runstart(bits, xbit)];
        L[base + (u32)r * Ww + (u32)xbit] = base + (rt >> 6) * Ww + (rt & 63);
    }
}

// ---------------- cross-tile boundary merges ----------------
// horizontal (tile-col) boundaries: per (img, b, row) word-edge check.
// vertical (tile-row) boundaries: per (img, b, wordcol) segment unions.
#define HITEMS (BATCH * 7 * 512)     // 57344
#define VITEMS (BATCH * 7 * 8)       // 896
__global__ void border_merge_kernel(const u64* __restrict__ mp, u32* L) {
    int e = blockIdx.x * blockDim.x + threadIdx.x;
    if (e < HITEMS) {
        int row = e & 511, b = (e >> 9) % 7, img = e / (512 * 7);
        u64 wa = mp[(size_t)img * WPI + (size_t)row * WROW + b];
        u64 wb = mp[(size_t)img * WPI + (size_t)row * WROW + b + 1];
        if ((wa >> 63) & wb & 1ULL) {
            u32 gl = (u32)img * IMG + (u32)row * Ww + (u32)(b * 64 + 63);
            uf_merge(L, gl, gl + 1);
        }
    } else if (e < HITEMS + VITEMS) {
        int v = e - HITEMS;
        int wc = v & 7, b = (v >> 3) % 7, img = v / 56;
        int ra = (b + 1) * 64 - 1;
        u64 a = mp[(size_t)img * WPI + (size_t)ra * WROW + wc];
        u64 bw = mp[(size_t)img * WPI + (size_t)(ra + 1) * WROW + wc];
        u64 ov = a & bw;
        u64 seg = ov & ~(ov << 1);
        while (seg) {
            int s = __ffsll(seg) - 1; seg &= seg - 1;
            u32 ga = (u32)img * IMG + (u32)ra * Ww + (u32)(wc * 64 + s);
            uf_merge(L, ga, ga + Ww);
        }
    }
}

// ---------------- flatten + count: wave-aggregated LDS hash ----------------
#define HASH_SZ 512
__global__ __launch_bounds__(256) void count_label_kernel(const u64* __restrict__ mp,
                                                          u32* __restrict__ L,
                                                          u32* __restrict__ counts) {
    __shared__ u32 keys[HASH_SZ];
    __shared__ u32 vals[HASH_SZ];
    int tid = threadIdx.x;
    for (int i = tid; i < HASH_SZ; i += 256) { keys[i] = 0xFFFFFFFFu; vals[i] = 0u; }
    __syncthreads();

    int g = blockIdx.x * 256 + tid;           // exact grid
    bool set = (mp[g >> 6] >> (g & 63)) & 1;
    u32 r = 0xFFFFFFFFu;
    if (set) {
        r = (u32)g;
        u32 p = L[r];
        while (p != r) { r = p; p = L[r]; }   // read-only chase (forest static)
        L[g] = r;                              // own slot only — race-free
    }
    bool pending = set;
    while (true) {
        u64 act = __ballot(pending);
        if (!act) break;
        int leader = __ffsll(act) - 1;
        u32 lr = __shfl(r, leader);
        bool mine = pending && (r == lr);
        u64 grp = __ballot(mine);
        if ((tid & 63) == leader) {
            u32 cnt = (u32)__popcll(grp);
            u32 h = (lr * 2654435761u) & (HASH_SZ - 1);
            while (true) {
                u32 k = atomicCAS(&keys[h], 0xFFFFFFFFu, lr);
                if (k == 0xFFFFFFFFu || k == lr) { atomicAdd(&vals[h], cnt); break; }
                h = (h + 1) & (HASH_SZ - 1);
            }
        }
        if (mine) pending = false;
    }
    __syncthreads();
    for (int i = tid; i < HASH_SZ; i += 256)
        if (keys[i] != 0xFFFFFFFFu) atomicAdd(&counts[keys[i]], vals[i]);
}

// ---------------- final: size filter + float write ----------------
// counts aliases out (d_out). Safe: a clobbered counts[r] is either 1.0f
// (bits 1065353216 > 262) or 0.0f (0 <= 262) — matches r's own keep verdict.
__global__ void final_kernel(const u64* __restrict__ mp, const u32* __restrict__ L,
                             const u32* __restrict__ counts, float* __restrict__ out) {
    int g = blockIdx.x * blockDim.x + threadIdx.x;   // exact grid
    bool set = (mp[g >> 6] >> (g & 63)) & 1;
    float v = 0.0f;
    if (set && counts[L[g]] > MIN_SIZE) v = 1.0f;
    out[g] = v;
}

extern "C" void kernel_launch(void* const* d_in, const int* in_sizes, int n_in,
                              void* d_out, int out_size, void* d_ws, size_t ws_size,
                              hipStream_t stream) {
    const float* x = (const float*)d_in[0];
    float* out = (float*)d_out;

    // ws layout: packed mask (512KB) | L (16MB)
    u64* mp = (u64*)d_ws;
    u32* L  = (u32*)(mp + TOT / 64);
    u32* counts = (u32*)d_out;     // aliases out — see final_kernel comment

    const int block = 256;

    vote_morph_kernel<<<BATCH * 8, 512, 0, stream>>>(x, mp);            // mp = final mask
    tile_ccl_kernel<<<BATCH * 64, block, 0, stream>>>(mp, L, counts);   // + counts=0
    border_merge_kernel<<<(HITEMS + VITEMS + block - 1) / block, block, 0, stream>>>(mp, L);
    count_label_kernel<<<TOT / block, block, 0, stream>>>(mp, L, counts);
    final_kernel<<<TOT / block, block, 0, stream>>>(mp, L, counts, out);
}

// Round 7
// 126.484 us; speedup vs baseline: 86.0521x; 1.1184x over previous
//
#include <hip/hip_runtime.h>

typedef unsigned long long u64;
typedef unsigned u32;

#define BATCH 16
#define Hh 512
#define Ww 512
#define IMG (Hh * Ww)          // 262144
#define TOT (BATCH * IMG)      // 4194304
#define WPI (IMG / 64)         // 4096 words per image
#define WROW 8                 // words per row
#define NWORDS (TOT / 64)      // 65536 total words
#define MIN_SIZE 262           // keep strictly greater
#define GHASH 65536            // global root->size hash (power of 2)
#define LHASH 2048             // per-block hash in count

#define BAND 16
#define HALO 4
#define BROWS (BAND + 2 * HALO)     // 24
#define BWORDS (BROWS * WROW)       // 192

// run start within a 64-bit row word: nearest zero at-or-below bit s, +1.
// (bit s must be set in `bits`.)
__device__ __forceinline__ u32 runstart(u64 bits, int s) {
    u64 ms = (s >= 63) ? ~0ULL : ((1ULL << (s + 1)) - 1);
    u64 nz = ~bits & ms;
    return nz ? (u32)(64 - __clzll(nz)) : 0u;
}

// run length starting at set bit s
__device__ __forceinline__ u32 runlen(u64 bits, int s) {
    u64 v = ~(bits >> s);
    return v ? (u32)(__ffsll(v) - 1) : (u32)(64 - s);
}

__device__ __forceinline__ u64 morph_word(const u64* M, int w, int rr, bool er) {
    const u64 B = er ? ~0ULL : 0ULL;
    int wx = w & 7;
    u64 cc = M[w];
    u64 lf = (cc << 1) | (wx > 0 ? (M[w - 1] >> 63) : (er ? 1ULL : 0ULL));
    u64 rt = (cc >> 1) | (wx < 7 ? (M[w + 1] << 63) : (er ? (1ULL << 63) : 0ULL));
    u64 up = (rr <= 0)      ? B : (w >= WROW          ? M[w - WROW] : B);
    u64 dn = (rr >= Hh - 1) ? B : (w < BWORDS - WROW  ? M[w + WROW] : B);
    return er ? (cc & lf & rt & up & dn) : (cc | lf | rt | up | dn);
}

// ---------------- fused vote + 4 morph passes, 16-row bands ----------------
// 16 img x 32 bands = 512 blocks, 256 threads. Also zeroes the global hash.
__global__ __launch_bounds__(256) void vote_morph_kernel(const float* __restrict__ x,
                                                         u64* __restrict__ mp,
                                                         u32* __restrict__ hkeys,
                                                         u32* __restrict__ hvals) {
    __shared__ u64 M[BWORDS];
    int blk = blockIdx.x;
    int img = blk >> 5;
    int r0  = (blk & 31) * BAND;
    int t = threadIdx.x, lane = t & 63, wv = t >> 6;

    // zero global hash: 512 blocks x 256 = 131072 = GHASH keys + GHASH vals
    {
        int idx = blk * 256 + t;
        if (idx < GHASH) hkeys[idx] = 0u;
        else             hvals[idx - GHASH] = 0u;
    }

    const float* xb = x + (size_t)img * 4 * IMG;
    for (int w = wv; w < BWORDS; w += 4) {           // word-col uniform per wave
        int rr = r0 - HALO + (w >> 3);
        u64 bits = 0;
        if (rr >= 0 && rr < Hh) {                    // wave-uniform branch
            size_t p = (size_t)rr * Ww + (size_t)(w & 7) * 64 + lane;
            bool p1 = xb[p + (size_t)IMG]     > 0.5f;
            bool p2 = xb[p + 2 * (size_t)IMG] > 0.5f;
            bool p3 = xb[p + 3 * (size_t)IMG] > 0.5f;
            bits = __ballot(p1 | (p2 & p3));
        }
        if (lane == 0) M[w] = bits;
    }
    __syncthreads();

    #pragma unroll
    for (int pass = 0; pass < 4; ++pass) {
        const bool er = (pass == 1 || pass == 2);    // close: D,E  open: E,D
        u64 res = 0;
        if (t < BWORDS) res = morph_word(M, t, r0 - HALO + (t >> 3), er);
        __syncthreads();
        if (t < BWORDS) M[t] = res;
        __syncthreads();
    }

    if (t < BAND * WROW)     // 128 owned words
        mp[(size_t)img * WPI + (size_t)r0 * WROW + t] = M[HALO * WROW + t];
}

// ---------------- union-find primitives (LDS or global) ----------------
template <typename P>
__device__ __forceinline__ u32 uf_find_halve(P L, u32 x) {
    while (true) {
        u32 p = L[x];
        if (p == x) return x;
        u32 gp = L[p];
        if (gp == p) return p;
        atomicMin(&L[x], gp);   // halving: gp <= p < x, monotone-safe
        x = gp;
    }
}

template <typename P>
__device__ __forceinline__ void uf_merge(P L, u32 a, u32 b) {
    while (true) {
        a = uf_find_halve(L, a);
        b = uf_find_halve(L, b);
        if (a == b) return;
        if (a > b) { u32 t = a; a = b; b = t; }   // a < b
        u32 old = atomicMin(&L[b], a);
        if (old == b) return;   // attached root b -> a
        b = old;
    }
}

// ---------------- per-tile run-based CCL in LDS ----------------
// Writes L ONLY at run-start nodes: L[node] = global root node id.
__global__ __launch_bounds__(256) void tile_ccl_kernel(const u64* __restrict__ mp,
                                                       u32* __restrict__ L) {
    __shared__ u64 mw[64];
    __shared__ u32 Ll[4096];
    int tile = blockIdx.x;        // 16 images * 64 tiles
    int img = tile >> 6, ty = (tile >> 3) & 7, tx = tile & 7;
    int tid = threadIdx.x;

    if (tid < 64)
        mw[tid] = mp[(size_t)img * WPI + (size_t)(ty * 64 + tid) * WROW + tx];
    __syncthreads();
    for (int i = tid; i < 4096; i += 256) Ll[i] = (u32)i;
    __syncthreads();

    if (tid >= 1 && tid < 64) {
        u64 a = mw[tid - 1], b = mw[tid];
        u64 ov = a & b;
        u64 seg = ov & ~(ov << 1);
        while (seg) {
            int s = __ffsll(seg) - 1; seg &= seg - 1;
            uf_merge((u32*)Ll, (u32)((tid - 1) * 64) + runstart(a, s),
                               (u32)(tid * 64)       + runstart(b, s));
        }
    }
    __syncthreads();

    u32 base = (u32)img * IMG + (u32)ty * 64 * Ww + (u32)tx * 64;
    if (tid < 64) {
        u64 bits = mw[tid];
        u64 st = bits & ~(bits << 1);               // run starts
        while (st) {
            int s = __ffsll(st) - 1; st &= st - 1;
            u32 n = (u32)(tid * 64 + s);
            u32 r = n, p = Ll[r];
            while (p != r) { r = p; p = Ll[r]; }    // read-only chase
            L[base + (u32)tid * Ww + (u32)s] = base + (r >> 6) * Ww + (r & 63);
        }
    }
}

// ---------------- cross-tile boundary merges (node-id based) ----------------
#define HITEMS (BATCH * 7 * 512)     // vertical tile boundaries, per row
#define VITEMS (BATCH * 7 * 8)       // horizontal tile boundaries, per word-col
__global__ void border_merge_kernel(const u64* __restrict__ mp, u32* L) {
    int e = blockIdx.x * blockDim.x + threadIdx.x;
    if (e < HITEMS) {
        int row = e & 511, b = (e >> 9) % 7, img = e / (512 * 7);
        const u64* rowp = mp + (size_t)img * WPI + (size_t)row * WROW;
        u64 wa = rowp[b], wb = rowp[b + 1];
        if (((wa >> 63) & 1ULL) && (wb & 1ULL)) {
            u32 pbase = (u32)img * IMG + (u32)row * Ww;
            uf_merge(L, pbase + (u32)(b * 64) + runstart(wa, 63),
                        pbase + (u32)((b + 1) * 64));          // bit0 -> runstart 0
        }
    } else if (e < HITEMS + VITEMS) {
        int v = e - HITEMS;
        int wc = v & 7, b = (v >> 3) % 7, img = v / 56;
        int ra = (b + 1) * 64 - 1;
        const u64* ib = mp + (size_t)img * WPI;
        u64 a  = ib[(size_t)ra * WROW + wc];
        u64 bw = ib[(size_t)(ra + 1) * WROW + wc];
        u64 ov = a & bw, seg = ov & ~(ov << 1);
        while (seg) {
            int s = __ffsll(seg) - 1; seg &= seg - 1;
            u32 ga = (u32)img * IMG + (u32)ra * Ww + (u32)(wc * 64);
            uf_merge(L, ga + runstart(a, s), ga + Ww + runstart(bw, s));
        }
    }
}

// ---------------- count: per-word runs -> LDS hash -> global hash ----------
__global__ __launch_bounds__(256) void count_kernel(const u64* __restrict__ mp,
                                                    u32* __restrict__ L,
                                                    u32* __restrict__ hkeys,
                                                    u32* __restrict__ hvals) {
    __shared__ u32 keys[LHASH];
    __shared__ u32 vals[LHASH];
    int tid = threadIdx.x;
    for (int i = tid; i < LHASH; i += 256) { keys[i] = 0xFFFFFFFFu; vals[i] = 0u; }
    __syncthreads();

    int widx = blockIdx.x * 256 + tid;        // exact grid: NWORDS threads
    u64 bits = mp[widx];
    u32 gbase = (u32)widx * 64;
    u64 st = bits & ~(bits << 1);
    while (st) {
        int s = __ffsll(st) - 1; st &= st - 1;
        u32 node = gbase + (u32)s;
        u32 r = node, p = L[r];
        while (p != r) { r = p; p = L[r]; }   // read-only chase (forest static)
        L[node] = r;                           // own-slot compress for final
        u32 len = runlen(bits, s);
        u32 h = (r * 2654435761u) & (LHASH - 1);
        while (true) {
            u32 k = atomicCAS(&keys[h], 0xFFFFFFFFu, r);
            if (k == 0xFFFFFFFFu || k == r) { atomicAdd(&vals[h], len); break; }
            h = (h + 1) & (LHASH - 1);
        }
    }
    __syncthreads();
    for (int i = tid; i < LHASH; i += 256) {
        u32 k = keys[i];
        if (k != 0xFFFFFFFFu) {
            u32 h = (k * 2654435761u) & (GHASH - 1);
            while (true) {
                u32 kk = atomicCAS(&hkeys[h], 0u, k + 1u);
                if (kk == 0u || kk == k + 1u) { atomicAdd(&hvals[h], vals[i]); break; }
                h = (h + 1) & (GHASH - 1);
            }
        }
    }
}

// ---------------- final: keep-mask per word, coalesced float4 writes -------
__global__ __launch_bounds__(256) void final_kernel(const u64* __restrict__ mp,
                                                    const u32* __restrict__ L,
                                                    const u32* __restrict__ hkeys,
                                                    const u32* __restrict__ hvals,
                                                    float* __restrict__ out) {
    __shared__ u64 km[256];
    int tid = threadIdx.x;
    int widx = blockIdx.x * 256 + tid;
    u64 bits = mp[widx];
    u32 gbase = (u32)widx * 64;
    u64 keep = 0;
    u64 st = bits & ~(bits << 1);
    while (st) {
        int s = __ffsll(st) - 1; st &= st - 1;
        u32 r = L[gbase + (u32)s];            // exact root (count compressed)
        u32 len = runlen(bits, s);
        u32 h = (r * 2654435761u) & (GHASH - 1);
        u32 sz = 0;
        while (true) {
            u32 k = hkeys[h];
            if (k == r + 1u) { sz = hvals[h]; break; }
            if (k == 0u) break;
            h = (h + 1) & (GHASH - 1);
        }
        if (sz > MIN_SIZE)
            keep |= (len == 64 ? ~0ULL : ((1ULL << len) - 1ULL)) << s;
    }
    km[tid] = keep;
    __syncthreads();
    float4* o4 = (float4*)out + (size_t)blockIdx.x * 4096;
    for (int i = tid; i < 4096; i += 256) {
        u32 nib = (u32)(km[i >> 4] >> ((i & 15) * 4)) & 0xFu;
        o4[i] = make_float4(nib & 1u ? 1.f : 0.f, nib & 2u ? 1.f : 0.f,
                            nib & 4u ? 1.f : 0.f, nib & 8u ? 1.f : 0.f);
    }
}

extern "C" void kernel_launch(void* const* d_in, const int* in_sizes, int n_in,
                              void* d_out, int out_size, void* d_ws, size_t ws_size,
                              hipStream_t stream) {
    const float* x = (const float*)d_in[0];
    float* out = (float*)d_out;

    // ws layout: packed mask (512KB) | L (16MB) | hkeys (256KB) | hvals (256KB)
    u64* mp = (u64*)d_ws;
    u32* L  = (u32*)(mp + NWORDS);
    u32* hkeys = L + TOT;
    u32* hvals = hkeys + GHASH;

    const int block = 256;

    vote_morph_kernel<<<BATCH * 32, block, 0, stream>>>(x, mp, hkeys, hvals);
    tile_ccl_kernel<<<BATCH * 64, block, 0, stream>>>(mp, L);
    border_merge_kernel<<<(HITEMS + VITEMS + block - 1) / block, block, 0, stream>>>(mp, L);
    count_kernel<<<NWORDS / block, block, 0, stream>>>(mp, L, hkeys, hvals);
    final_kernel<<<NWORDS / block, block, 0, stream>>>(mp, L, hkeys, hvals, out);
}